// Round 1
// baseline (179.359 us; speedup 1.0000x reference)
//
#include <hip/hip_runtime.h>
#include <hip/hip_bf16.h>

#define NB 8
#define NS 4096
#define ND 64

typedef short v4s __attribute__((ext_vector_type(4)));
typedef float v4f __attribute__((ext_vector_type(4)));

__device__ __forceinline__ short f2b(float f) {
    unsigned int u = __float_as_uint(f);
    u += 0x7FFFu + ((u >> 16) & 1u);   // round-to-nearest-even
    return (short)(u >> 16);
}

__global__ __launch_bounds__(256) void fa64_kernel(
        const float* __restrict__ Q, const float* __restrict__ K,
        const float* __restrict__ V, float* __restrict__ O) {
    // padded to 68 shorts/row: row stride 34 dwords == 2 (mod 32) -> b64 reads
    // across 16 rows hit all 32 banks uniformly (4-way = b64 minimum)
    __shared__ __align__(16) short Ksh[64][68];   // K tile  [key][d]
    __shared__ __align__(16) short Vt [64][68];   // V tile transposed [d][key]
    __shared__ __align__(16) short Psh[4][16][68];// per-wave P transpose buffer

    const int t    = threadIdx.x;
    const int w    = t >> 6;      // wave 0..3
    const int lane = t & 63;
    const int lc   = lane & 15;   // MFMA col lane
    const int h    = lane >> 4;   // MFMA lane group 0..3

    const int bid = blockIdx.x;
    const int b   = bid & 7;            // batch -> XCD (round-robin dispatch)
    const int q0  = (bid >> 3) * 64 + w * 16;

    const float* Qb = Q + (size_t)b * NS * ND;
    const float* Kb = K + (size_t)b * NS * ND;
    const float* Vb = V + (size_t)b * NS * ND;

    // Q fragments (A operand): A[row=lc][k=16c+4h+e]
    v4s qa[4];
    {
        const float* qrow = Qb + (size_t)(q0 + lc) * ND + 4 * h;
        #pragma unroll
        for (int c = 0; c < 4; ++c) {
            v4f x = *(const v4f*)(qrow + 16 * c);
            v4s a;
            a[0] = f2b(x[0]); a[1] = f2b(x[1]);
            a[2] = f2b(x[2]); a[3] = f2b(x[3]);
            qa[c] = a;
        }
    }

    v4f o[4];
    #pragma unroll
    for (int g = 0; g < 4; ++g) o[g] = (v4f){0.f, 0.f, 0.f, 0.f};
    float m2[4]   = {-INFINITY, -INFINITY, -INFINITY, -INFINITY};
    float lsum[4] = {0.f, 0.f, 0.f, 0.f};

    const float SCL = 0.125f * 1.4426950408889634f;  // 1/sqrt(64) * log2(e)

    const int sc4 = t & 15;   // staging: 16B column group
    const int sr  = t >> 4;   // staging: row group 0..15

    for (int kt = 0; kt < NS / 64; ++kt) {
        const int k0 = kt * 64;
        __syncthreads();   // prior tile's LDS reads done before overwrite
        // ---- stage K tile [64 keys][64 d] (coalesced float4, cvt to bf16) ----
        #pragma unroll
        for (int i = 0; i < 4; ++i) {
            const int rr = sr + 16 * i;
            v4f x = *(const v4f*)(Kb + (size_t)(k0 + rr) * ND + sc4 * 4);
            v4s a;
            a[0] = f2b(x[0]); a[1] = f2b(x[1]);
            a[2] = f2b(x[2]); a[3] = f2b(x[3]);
            *(v4s*)&Ksh[rr][sc4 * 4] = a;
        }
        // ---- stage V^T tile [64 d][64 keys] via 4x4 register transpose ----
        {
            float xv[4][4];
            #pragma unroll
            for (int i = 0; i < 4; ++i) {
                v4f x = *(const v4f*)(Vb + (size_t)(k0 + sr * 4 + i) * ND + sc4 * 4);
                xv[i][0] = x[0]; xv[i][1] = x[1]; xv[i][2] = x[2]; xv[i][3] = x[3];
            }
            #pragma unroll
            for (int j = 0; j < 4; ++j) {
                v4s a;
                a[0] = f2b(xv[0][j]); a[1] = f2b(xv[1][j]);
                a[2] = f2b(xv[2][j]); a[3] = f2b(xv[3][j]);
                *(v4s*)&Vt[sc4 * 4 + j][sr * 4] = a;
            }
        }
        __syncthreads();

        // ---- S = Q K^T, 16 queries x 64 keys ----
        v4f s[4];
        #pragma unroll
        for (int g = 0; g < 4; ++g) {
            v4f acc = (v4f){0.f, 0.f, 0.f, 0.f};
            #pragma unroll
            for (int c = 0; c < 4; ++c) {
                // B[k=16c+4h+e][key=16g+lc] = Ksh[16g+lc][16c+4h+e]
                v4s kf = *(const v4s*)&Ksh[16 * g + lc][16 * c + 4 * h];
                acc = __builtin_amdgcn_mfma_f32_16x16x16bf16_1k(qa[c], kf, acc, 0, 0, 0);
            }
            s[g] = acc;   // s[g][r]: row 4h+r, col 16g+lc
        }

        // ---- online softmax (log2 domain) ----
        float alpha[4];
        #pragma unroll
        for (int r = 0; r < 4; ++r) {
            float t0 = s[0][r] * SCL, t1 = s[1][r] * SCL,
                  t2 = s[2][r] * SCL, t3 = s[3][r] * SCL;
            float tmax = fmaxf(fmaxf(t0, t1), fmaxf(t2, t3));
            #pragma unroll
            for (int off = 1; off < 16; off <<= 1)
                tmax = fmaxf(tmax, __shfl_xor(tmax, off, 64));
            const float mn = fmaxf(m2[r], tmax);
            alpha[r] = exp2f(m2[r] - mn);   // first iter: exp2(-inf)=0
            const float p0 = exp2f(t0 - mn), p1 = exp2f(t1 - mn);
            const float p2 = exp2f(t2 - mn), p3 = exp2f(t3 - mn);
            float rs = (p0 + p1) + (p2 + p3);
            #pragma unroll
            for (int off = 1; off < 16; off <<= 1)
                rs += __shfl_xor(rs, off, 64);
            lsum[r] = alpha[r] * lsum[r] + rs;
            m2[r] = mn;
            const int pr = 4 * h + r;   // D-layout row -> P row in LDS
            Psh[w][pr][lc]      = f2b(p0);
            Psh[w][pr][16 + lc] = f2b(p1);
            Psh[w][pr][32 + lc] = f2b(p2);
            Psh[w][pr][48 + lc] = f2b(p3);
        }
        #pragma unroll
        for (int g = 0; g < 4; ++g) {
            o[g][0] *= alpha[0]; o[g][1] *= alpha[1];
            o[g][2] *= alpha[2]; o[g][3] *= alpha[3];
        }

        // ---- O += P V ----
        #pragma unroll
        for (int c2 = 0; c2 < 4; ++c2) {
            // A[row=q=lc][k=key=16c2+4h+e]
            v4s pa = *(const v4s*)&Psh[w][lc][16 * c2 + 4 * h];
            #pragma unroll
            for (int g = 0; g < 4; ++g) {
                // B[k=key][n=d=16g+lc] = Vt[16g+lc][16c2+4h+e]
                v4s vf = *(const v4s*)&Vt[16 * g + lc][16 * c2 + 4 * h];
                o[g] = __builtin_amdgcn_mfma_f32_16x16x16bf16_1k(pa, vf, o[g], 0, 0, 0);
            }
        }
    }

    // ---- epilogue: normalize and store ----
    #pragma unroll
    for (int r = 0; r < 4; ++r) {
        const float inv = 1.0f / lsum[r];
        float* orow = O + ((size_t)b * NS + q0 + 4 * h + r) * ND;
        #pragma unroll
        for (int g = 0; g < 4; ++g)
            orow[16 * g + lc] = o[g][r] * inv;
    }
}

extern "C" void kernel_launch(void* const* d_in, const int* in_sizes, int n_in,
                              void* d_out, int out_size, void* d_ws, size_t ws_size,
                              hipStream_t stream) {
    const float* q = (const float*)d_in[0];
    const float* k = (const float*)d_in[1];
    const float* v = (const float*)d_in[2];
    float* out = (float*)d_out;
    dim3 grid(NB * (NS / 64));   // 512 blocks: batch = bid&7 (XCD-local K/V)
    dim3 block(256);             // 4 waves, 16 query rows each
    hipLaunchKernelGGL(fa64_kernel, grid, block, 0, stream, q, k, v, out);
}

// Round 2
// 84.243 us; speedup vs baseline: 2.1291x; 2.1291x over previous
//
#include <hip/hip_runtime.h>
#include <hip/hip_bf16.h>

#define NB 8
#define NS 4096
#define ND 64
#define NT (NS / 64)
#define LDP 72   // LDS row pitch in shorts: 144 B = 16B-aligned, conflict-minimal

typedef short v4s __attribute__((ext_vector_type(4)));
typedef short v8s __attribute__((ext_vector_type(8)));
typedef float v4f __attribute__((ext_vector_type(4)));

__device__ __forceinline__ v4s pk4(float a, float b, float c, float d) {
    union { __hip_bfloat162 h[2]; v4s v; } u;
    float2 p0; p0.x = a; p0.y = b;
    float2 p1; p1.x = c; p1.y = d;
    u.h[0] = __float22bfloat162_rn(p0);
    u.h[1] = __float22bfloat162_rn(p1);
    return u.v;
}
__device__ __forceinline__ v8s pk8(v4f x0, v4f x1) {
    union { v4s q[2]; v8s v; } u;
    u.q[0] = pk4(x0[0], x0[1], x0[2], x0[3]);
    u.q[1] = pk4(x1[0], x1[1], x1[2], x1[3]);
    return u.v;
}

// ---- prepass: K (f32) -> Kbf (bf16, row-major) ----
__global__ __launch_bounds__(256) void prep_k(const float* __restrict__ K,
                                              short* __restrict__ Kb) {
    size_t n = ((size_t)blockIdx.x * 256 + threadIdx.x) * 8;
    v4f x0 = *(const v4f*)(K + n);
    v4f x1 = *(const v4f*)(K + n + 4);
    *(v8s*)&Kb[n] = pk8(x0, x1);
}

// ---- prepass: V (f32, [b][s][d]) -> Vt (bf16, [b][d][s]) ----
__global__ __launch_bounds__(256) void prep_v(const float* __restrict__ V,
                                              short* __restrict__ Vt) {
    __shared__ short T[64][LDP];
    const int b  = blockIdx.x >> 6;
    const int s0 = (blockIdx.x & 63) * 64;
    const int t  = threadIdx.x;
    #pragma unroll
    for (int i = 0; i < 2; ++i) {
        int n = i * 256 + t;
        int r = n >> 3, c8 = (n & 7) * 8;
        const float* src = V + ((size_t)b * NS + s0 + r) * ND + c8;
        v4f x0 = *(const v4f*)src;
        v4f x1 = *(const v4f*)(src + 4);
        *(v8s*)&T[r][c8] = pk8(x0, x1);
    }
    __syncthreads();
    #pragma unroll
    for (int i = 0; i < 2; ++i) {
        int n = i * 256 + t;
        int d = n >> 3, kc8 = (n & 7) * 8;
        v8s a;
        #pragma unroll
        for (int j = 0; j < 8; ++j) a[j] = T[kc8 + j][d];
        *(v8s*)&Vt[((size_t)b * ND + d) * NS + s0 + kc8] = a;
    }
}

template <bool PRE>
__global__ __launch_bounds__(256) void fa_main(
        const float* __restrict__ Q, const float* __restrict__ K,
        const float* __restrict__ V, const short* __restrict__ Kbf,
        const short* __restrict__ Vtb, float* __restrict__ O) {
    __shared__ short Ksh[64][LDP];   // K tile  [key][d]
    __shared__ short Vsh[64][LDP];   // V^T tile [d][key]

    const int t    = threadIdx.x;
    const int lane = t & 63;
    const int w    = t >> 6;
    const int lc   = lane & 15;      // query lane (B-operand col)
    const int h    = lane >> 4;      // k-group 0..3

    const int b  = blockIdx.x & 7;                  // batch -> XCD locality
    const int q0 = (blockIdx.x >> 3) * 128 + w * 32; // wave owns 32 queries

    const float SCL = 0.125f * 1.4426950408889634f; // 1/sqrt(64) * log2(e)

    // Q B-frags (scale folded in): qb[u][c] slot e = Q[q0+16u+lc][32c+8h+e]*SCL
    v8s qb[2][2];
    #pragma unroll
    for (int u = 0; u < 2; ++u) {
        const float* qrow = Q + ((size_t)b * NS + q0 + 16 * u + lc) * ND + 8 * h;
        #pragma unroll
        for (int c = 0; c < 2; ++c) {
            v4f x0 = *(const v4f*)(qrow + 32 * c);
            v4f x1 = *(const v4f*)(qrow + 32 * c + 4);
            x0 = x0 * SCL; x1 = x1 * SCL;
            qb[u][c] = pk8(x0, x1);
        }
    }

    v4f o[2][4];
    #pragma unroll
    for (int u = 0; u < 2; ++u)
        #pragma unroll
        for (int g = 0; g < 4; ++g) o[u][g] = (v4f){0.f, 0.f, 0.f, 0.f};
    float m[2]    = {-INFINITY, -INFINITY};
    float lsum[2] = {0.f, 0.f};

    const int srow = t >> 2;   // staging row 0..63
    const int sc   = t & 3;    // staging 16B col group

    v8s kreg[2], vreg[2];
    if constexpr (PRE) {
        #pragma unroll
        for (int i = 0; i < 2; ++i) {
            kreg[i] = *(const v8s*)&Kbf[((size_t)b * NS + srow) * ND + (sc + 4 * i) * 8];
            vreg[i] = *(const v8s*)&Vtb[((size_t)b * ND + srow) * NS + (sc + 4 * i) * 8];
        }
    }

    for (int kt = 0; kt < NT; ++kt) {
        const int k0 = kt * 64;
        __syncthreads();                         // prior tile's readers done
        if constexpr (PRE) {
            #pragma unroll
            for (int i = 0; i < 2; ++i) {
                *(v8s*)&Ksh[srow][(sc + 4 * i) * 8] = kreg[i];
                *(v8s*)&Vsh[srow][(sc + 4 * i) * 8] = vreg[i];
            }
        } else {
            #pragma unroll
            for (int i = 0; i < 4; ++i) {
                int n = i * 256 + t;
                int row = n >> 4, c4 = (n & 15) * 4;
                v4f x = *(const v4f*)(K + ((size_t)b * NS + k0 + row) * ND + c4);
                *(v4s*)&Ksh[row][c4] = pk4(x[0], x[1], x[2], x[3]);
            }
            const int sr = t >> 4, sc4 = t & 15;
            float xv[4][4];
            #pragma unroll
            for (int i = 0; i < 4; ++i) {
                v4f x = *(const v4f*)(V + ((size_t)b * NS + k0 + sr * 4 + i) * ND + sc4 * 4);
                xv[i][0] = x[0]; xv[i][1] = x[1]; xv[i][2] = x[2]; xv[i][3] = x[3];
            }
            #pragma unroll
            for (int j = 0; j < 4; ++j)
                *(v4s*)&Vsh[sc4 * 4 + j][sr * 4] = pk4(xv[0][j], xv[1][j], xv[2][j], xv[3][j]);
        }
        __syncthreads();
        if constexpr (PRE) {
            if (kt + 1 < NT) {   // prefetch next tile under this tile's compute
                #pragma unroll
                for (int i = 0; i < 2; ++i) {
                    kreg[i] = *(const v8s*)&Kbf[((size_t)b * NS + k0 + 64 + srow) * ND + (sc + 4 * i) * 8];
                    vreg[i] = *(const v8s*)&Vtb[((size_t)b * ND + srow) * NS + k0 + 64 + (sc + 4 * i) * 8];
                }
            }
        }

        // ---- S^T = K Q^T: lane holds 16 scores for query lc, keys 16g+4h+r ----
        float p[2][4][4];
        #pragma unroll
        for (int g = 0; g < 4; ++g) {
            v4f a0 = (v4f){0.f, 0.f, 0.f, 0.f};
            v4f a1 = (v4f){0.f, 0.f, 0.f, 0.f};
            #pragma unroll
            for (int c = 0; c < 2; ++c) {
                v8s ka = *(const v8s*)&Ksh[16 * g + lc][32 * c + 8 * h];
                a0 = __builtin_amdgcn_mfma_f32_16x16x32_bf16(ka, qb[0][c], a0, 0, 0, 0);
                a1 = __builtin_amdgcn_mfma_f32_16x16x32_bf16(ka, qb[1][c], a1, 0, 0, 0);
            }
            #pragma unroll
            for (int r = 0; r < 4; ++r) { p[0][g][r] = a0[r]; p[1][g][r] = a1[r]; }
        }

        // ---- online softmax, deferred rescale (THR=8 in log2 domain) ----
        #pragma unroll
        for (int u = 0; u < 2; ++u) {
            float pm = p[u][0][0];
            #pragma unroll
            for (int g = 0; g < 4; ++g)
                #pragma unroll
                for (int r = 0; r < 4; ++r) pm = fmaxf(pm, p[u][g][r]);
            pm = fmaxf(pm, __shfl_xor(pm, 16));
            pm = fmaxf(pm, __shfl_xor(pm, 32));
            if (__any(pm > m[u] + 8.0f)) {
                float mn = fmaxf(m[u], pm);
                float al = __builtin_amdgcn_exp2f(m[u] - mn);  // first tile: 0
                #pragma unroll
                for (int g = 0; g < 4; ++g) o[u][g] = o[u][g] * al;
                lsum[u] *= al;
                m[u] = mn;
            }
            float rs = 0.f;
            #pragma unroll
            for (int g = 0; g < 4; ++g)
                #pragma unroll
                for (int r = 0; r < 4; ++r) {
                    p[u][g][r] = __builtin_amdgcn_exp2f(p[u][g][r] - m[u]);
                    rs += p[u][g][r];
                }
            lsum[u] += rs;   // h-partial; reduced in epilogue
        }

        // ---- O^T += V^T P^T: P^T feeds B directly from registers ----
        #pragma unroll
        for (int c2 = 0; c2 < 2; ++c2) {
            union { v4s q[2]; v8s v; } pb0, pb1;
            pb0.q[0] = pk4(p[0][2*c2][0],   p[0][2*c2][1],   p[0][2*c2][2],   p[0][2*c2][3]);
            pb0.q[1] = pk4(p[0][2*c2+1][0], p[0][2*c2+1][1], p[0][2*c2+1][2], p[0][2*c2+1][3]);
            pb1.q[0] = pk4(p[1][2*c2][0],   p[1][2*c2][1],   p[1][2*c2][2],   p[1][2*c2][3]);
            pb1.q[1] = pk4(p[1][2*c2+1][0], p[1][2*c2+1][1], p[1][2*c2+1][2], p[1][2*c2+1][3]);
            #pragma unroll
            for (int g = 0; g < 4; ++g) {
                union { v4s q[2]; v8s v; } va;   // slot-matched to P^T's key layout
                va.q[0] = *(const v4s*)&Vsh[16 * g + lc][32 * c2 + 4 * h];
                va.q[1] = *(const v4s*)&Vsh[16 * g + lc][32 * c2 + 16 + 4 * h];
                o[0][g] = __builtin_amdgcn_mfma_f32_16x16x32_bf16(va.v, pb0.v, o[0][g], 0, 0, 0);
                o[1][g] = __builtin_amdgcn_mfma_f32_16x16x32_bf16(va.v, pb1.v, o[1][g], 0, 0, 0);
            }
        }
    }

    // ---- epilogue: reduce lsum across h-lanes, normalize, store ----
    #pragma unroll
    for (int u = 0; u < 2; ++u) {
        float ls = lsum[u];
        ls += __shfl_xor(ls, 16);
        ls += __shfl_xor(ls, 32);
        float inv = 1.0f / ls;
        float* orow = O + ((size_t)b * NS + q0 + 16 * u + lc) * ND;
        #pragma unroll
        for (int g = 0; g < 4; ++g) {
            v4f rr = o[u][g] * inv;            // lane holds d = 16g+4h+0..3
            *(v4f*)(orow + 16 * g + 4 * h) = rr;
        }
    }
}

extern "C" void kernel_launch(void* const* d_in, const int* in_sizes, int n_in,
                              void* d_out, int out_size, void* d_ws, size_t ws_size,
                              hipStream_t stream) {
    const float* q = (const float*)d_in[0];
    const float* k = (const float*)d_in[1];
    const float* v = (const float*)d_in[2];
    float* out = (float*)d_out;
    const size_t tot  = (size_t)NB * NS * ND;        // 2,097,152 elems
    const size_t need = 2 * tot * sizeof(short);     // 8 MB (Kbf + Vt)
    if (ws_size >= need) {
        short* kb = (short*)d_ws;
        short* vt = kb + tot;
        hipLaunchKernelGGL(prep_k, dim3((unsigned)(tot / 2048)), dim3(256), 0, stream, k, kb);
        hipLaunchKernelGGL(prep_v, dim3(NB * (NS / 64)), dim3(256), 0, stream, v, vt);
        hipLaunchKernelGGL(fa_main<true>, dim3(NB * (NS / 128)), dim3(256), 0, stream,
                           q, k, v, kb, vt, out);
    } else {
        hipLaunchKernelGGL(fa_main<false>, dim3(NB * (NS / 128)), dim3(256), 0, stream,
                           q, k, v, (const short*)nullptr, (const short*)nullptr, out);
    }
}

// Round 3
// 73.628 us; speedup vs baseline: 2.4360x; 1.1442x over previous
//
#include <hip/hip_runtime.h>
#include <hip/hip_bf16.h>

#define NB 8
#define NS 4096
#define ND 64
#define NROW (NB * NS)

typedef short v4s __attribute__((ext_vector_type(4)));
typedef short v8s __attribute__((ext_vector_type(8)));
typedef float v4f __attribute__((ext_vector_type(4)));

static __device__ __forceinline__ v4s pk4(float a, float b, float c, float d) {
    union { __hip_bfloat162 h[2]; v4s v; } u;
    float2 p0; p0.x = a; p0.y = b;
    float2 p1; p1.x = c; p1.y = d;
    u.h[0] = __float22bfloat162_rn(p0);
    u.h[1] = __float22bfloat162_rn(p1);
    return u.v;
}
static __device__ __forceinline__ v8s pk8(v4f x0, v4f x1) {
    union { v4s q[2]; v8s v; } u;
    u.q[0] = pk4(x0[0], x0[1], x0[2], x0[3]);
    u.q[1] = pk4(x1[0], x1[1], x1[2], x1[3]);
    return u.v;
}

__device__ __forceinline__ void gl16(const void* g, void* s) {
    __builtin_amdgcn_global_load_lds(
        (const __attribute__((address_space(1))) void*)g,
        (__attribute__((address_space(3))) void*)s, 16, 0, 0);
}

// ---- Q -> bf16 * (1/8 * log2e), row-major ----
__global__ __launch_bounds__(256) void prep_q(const float* __restrict__ Q,
                                              short* __restrict__ Qb) {
    const float SCL = 0.125f * 1.4426950408889634f;
    size_t n = (size_t)blockIdx.x * 256 + threadIdx.x;
    v4f x0 = *(const v4f*)(Q + n * 8);
    v4f x1 = *(const v4f*)(Q + n * 8 + 4);
    *(v8s*)&Qb[n * 8] = pk8(x0 * SCL, x1 * SCL);
}

// ---- K -> bf16, per-64-key-tile stream, 16B granules XOR-swizzled by row ----
__global__ __launch_bounds__(256) void prep_k(const float* __restrict__ K,
                                              short* __restrict__ Kb) {
    size_t n = (size_t)blockIdx.x * 256 + threadIdx.x;
    int g = (int)(n & 7);            // d-granule 0..7
    size_t r = n >> 3;               // global key row
    int row = (int)(r & 63);
    size_t tile = r >> 6;
    v4f x0 = *(const v4f*)(K + n * 8);
    v4f x1 = *(const v4f*)(K + n * 8 + 4);
    *(v8s*)&Kb[tile * 4096 + row * 64 + ((g ^ (row & 7)) << 3)] = pk8(x0, x1);
}

// ---- V -> bf16 transposed [d][key] per tile, swizzled granules ----
__global__ __launch_bounds__(256) void prep_v(const float* __restrict__ V,
                                              short* __restrict__ Vt) {
    __shared__ short T[64][72];
    const int bt = blockIdx.x;           // b*64 + tile
    const int b  = bt >> 6;
    const int s0 = (bt & 63) * 64;
    const int t  = threadIdx.x;
    #pragma unroll
    for (int i = 0; i < 2; ++i) {
        int n = i * 256 + t;
        int r = n >> 3, c8 = (n & 7) * 8;
        const float* src = V + ((size_t)b * NS + s0 + r) * ND + c8;
        v4f x0 = *(const v4f*)src;
        v4f x1 = *(const v4f*)(src + 4);
        *(v8s*)&T[r][c8] = pk8(x0, x1);
    }
    __syncthreads();
    #pragma unroll
    for (int i = 0; i < 2; ++i) {
        int n = i * 256 + t;
        int d = n >> 3, kg = n & 7;      // kg = key granule
        v8s a;
        #pragma unroll
        for (int j = 0; j < 8; ++j) a[j] = T[kg * 8 + j][d];
        *(v8s*)&Vt[(size_t)bt * 4096 + d * 64 + ((kg ^ (d & 7)) << 3)] = a;
    }
}

// ---- main flash kernel: 32 q/wave, 128 q/block, split-K ----
template <int SPLIT>
__global__ __launch_bounds__(256, 4) void fa_main(
        const short* __restrict__ Qbf, const short* __restrict__ Kbf,
        const short* __restrict__ Vtb, float* __restrict__ O,
        float* __restrict__ Opart, float2* __restrict__ stats) {
    __shared__ short Ksh[2][4096];
    __shared__ short Vsh[2][4096];

    const int t    = threadIdx.x;
    const int lane = t & 63;
    const int w    = t >> 6;
    const int lc   = lane & 15;
    const int h    = lane >> 4;
    const int lw   = lc & 7;

    const int bid  = blockIdx.x;
    const int b    = bid & 7;                 // batch -> XCD (KV L2-resident)
    const int rest = bid >> 3;
    const int sp   = rest % SPLIT;
    const int qblk = rest / SPLIT;
    const int q0   = qblk * 128 + w * 32;

    const int TPS = (NS / 64) / SPLIT;
    const int kt0 = sp * TPS;

    // Q fragments (scale folded in prepass): qf[u][c] = Q[q0+16u+lc][32c+8h+e]
    v8s qf[2][2];
    #pragma unroll
    for (int u = 0; u < 2; ++u) {
        const short* qrow = Qbf + ((size_t)b * NS + q0 + 16 * u + lc) * ND + 8 * h;
        qf[u][0] = *(const v8s*)(qrow);
        qf[u][1] = *(const v8s*)(qrow + 32);
    }

    v4f o[2][4];
    #pragma unroll
    for (int u = 0; u < 2; ++u)
        #pragma unroll
        for (int g = 0; g < 4; ++g) o[u][g] = (v4f){0.f, 0.f, 0.f, 0.f};
    float m[2]    = {-INFINITY, -INFINITY};
    float lsum[2] = {0.f, 0.f};

    auto stage = [&](int kt, int buf) {
        const size_t kb = ((size_t)b * (NS / 64) + kt) * 4096;
        const short* ks = Kbf + kb + w * 1024 + lane * 8;
        const short* vs = Vtb + kb + w * 1024 + lane * 8;
        short* kd = &Ksh[buf][w * 1024];
        short* vd = &Vsh[buf][w * 1024];
        gl16(ks,       kd);
        gl16(ks + 512, kd + 512);
        gl16(vs,       vd);
        gl16(vs + 512, vd + 512);
    };

    stage(kt0, 0);

    auto body = [&](int i, int cur) {
        __syncthreads();   // compiler drains vmcnt(0): buf[cur] staged by all waves
        if (i + 1 < TPS) stage(kt0 + i + 1, cur ^ 1);

        // ---- S^T = K Q^T: lane holds scores for query lc, keys 16g+4h+r ----
        float p[2][4][4];
        #pragma unroll
        for (int g = 0; g < 4; ++g) {
            v4f a0 = (v4f){0.f, 0.f, 0.f, 0.f};
            v4f a1 = (v4f){0.f, 0.f, 0.f, 0.f};
            const int row = 16 * g + lc;
            #pragma unroll
            for (int c = 0; c < 2; ++c) {
                v8s ka = *(const v8s*)&Ksh[cur][row * 64 + (((4 * c + h) ^ lw) << 3)];
                a0 = __builtin_amdgcn_mfma_f32_16x16x32_bf16(ka, qf[0][c], a0, 0, 0, 0);
                a1 = __builtin_amdgcn_mfma_f32_16x16x32_bf16(ka, qf[1][c], a1, 0, 0, 0);
            }
            #pragma unroll
            for (int r = 0; r < 4; ++r) { p[0][g][r] = a0[r]; p[1][g][r] = a1[r]; }
        }

        // ---- online softmax (log2 domain), deferred rescale THR=8 ----
        #pragma unroll
        for (int u = 0; u < 2; ++u) {
            float pm = p[u][0][0];
            #pragma unroll
            for (int g = 0; g < 4; ++g)
                #pragma unroll
                for (int r = 0; r < 4; ++r) pm = fmaxf(pm, p[u][g][r]);
            pm = fmaxf(pm, __shfl_xor(pm, 16));
            pm = fmaxf(pm, __shfl_xor(pm, 32));
            if (__any(pm > m[u] + 8.0f)) {
                float mn = fmaxf(m[u], pm);
                float al = __builtin_amdgcn_exp2f(m[u] - mn);   // first tile: 0
                #pragma unroll
                for (int g = 0; g < 4; ++g) o[u][g] = o[u][g] * al;
                lsum[u] *= al;
                m[u] = mn;
            }
            float rs = 0.f;
            #pragma unroll
            for (int g = 0; g < 4; ++g)
                #pragma unroll
                for (int r = 0; r < 4; ++r) {
                    p[u][g][r] = __builtin_amdgcn_exp2f(p[u][g][r] - m[u]);
                    rs += p[u][g][r];
                }
            lsum[u] += rs;   // h-partial; reduced in epilogue
        }

        // ---- O^T += V^T P^T (P^T from registers, slot-matched V reads) ----
        #pragma unroll
        for (int c2 = 0; c2 < 2; ++c2) {
            union { v4s q[2]; v8s v; } pb0, pb1;
            pb0.q[0] = pk4(p[0][2*c2][0],   p[0][2*c2][1],   p[0][2*c2][2],   p[0][2*c2][3]);
            pb0.q[1] = pk4(p[0][2*c2+1][0], p[0][2*c2+1][1], p[0][2*c2+1][2], p[0][2*c2+1][3]);
            pb1.q[0] = pk4(p[1][2*c2][0],   p[1][2*c2][1],   p[1][2*c2][2],   p[1][2*c2][3]);
            pb1.q[1] = pk4(p[1][2*c2+1][0], p[1][2*c2+1][1], p[1][2*c2+1][2], p[1][2*c2+1][3]);
            #pragma unroll
            for (int g = 0; g < 4; ++g) {
                const int row = 16 * g + lc;
                const int G0 = (4 * c2 + (h >> 1)) ^ lw;
                const int G1 = (4 * c2 + 2 + (h >> 1)) ^ lw;
                union { v4s q[2]; v8s v; } va;
                va.q[0] = *(const v4s*)&Vsh[cur][row * 64 + (G0 << 3) + 4 * (h & 1)];
                va.q[1] = *(const v4s*)&Vsh[cur][row * 64 + (G1 << 3) + 4 * (h & 1)];
                o[0][g] = __builtin_amdgcn_mfma_f32_16x16x32_bf16(va.v, pb0.v, o[0][g], 0, 0, 0);
                o[1][g] = __builtin_amdgcn_mfma_f32_16x16x32_bf16(va.v, pb1.v, o[1][g], 0, 0, 0);
            }
        }
    };

    for (int i = 0; i < TPS; i += 2) { body(i, 0); body(i + 1, 1); }

    // ---- epilogue ----
    #pragma unroll
    for (int u = 0; u < 2; ++u) {
        float ls = lsum[u];
        ls += __shfl_xor(ls, 16);
        ls += __shfl_xor(ls, 32);
        const int q = q0 + 16 * u + lc;
        if constexpr (SPLIT == 1) {
            const float inv = 1.0f / ls;
            float* orow = O + ((size_t)b * NS + q) * ND;
            #pragma unroll
            for (int g = 0; g < 4; ++g) {
                v4f rr = o[u][g] * inv;
                *(v4f*)(orow + 16 * g + 4 * h) = rr;
            }
        } else {
            float* op = Opart + (((size_t)sp * NB + b) * NS + q) * ND;
            #pragma unroll
            for (int g = 0; g < 4; ++g)
                *(v4f*)(op + 16 * g + 4 * h) = o[u][g];
            if (h == 0) {
                float2 st; st.x = m[u]; st.y = ls;
                stats[(size_t)sp * NROW + (size_t)b * NS + q] = st;
            }
        }
    }
}

// ---- split-K combine ----
__global__ __launch_bounds__(256) void fa_combine(const float* __restrict__ Opart,
        const float2* __restrict__ stats, float* __restrict__ O, int split) {
    const int idx = blockIdx.x * 256 + threadIdx.x;
    const int row = idx >> 4;
    const int d4  = (idx & 15) * 4;
    float M = -INFINITY;
    for (int s = 0; s < split; ++s)
        M = fmaxf(M, stats[(size_t)s * NROW + row].x);
    float l = 0.f;
    v4f acc = (v4f){0.f, 0.f, 0.f, 0.f};
    for (int s = 0; s < split; ++s) {
        float2 st = stats[(size_t)s * NROW + row];
        float al = exp2f(st.x - M);
        l += al * st.y;
        v4f x = *(const v4f*)&Opart[((size_t)s * NROW + row) * ND + d4];
        acc += x * al;
    }
    v4f r = acc * (1.0f / l);
    *(v4f*)&O[(size_t)row * ND + d4] = r;
}

// ---- no-workspace fallback (R2 structure, inline f32->bf16 staging) ----
__global__ __launch_bounds__(256) void fa_fallback(
        const float* __restrict__ Q, const float* __restrict__ K,
        const float* __restrict__ V, float* __restrict__ O) {
    __shared__ short Ksh[64][72];
    __shared__ short Vsh[64][72];
    const int t = threadIdx.x;
    const int lane = t & 63;
    const int w = t >> 6;
    const int lc = lane & 15;
    const int h  = lane >> 4;
    const int b  = blockIdx.x & 7;
    const int q0 = (blockIdx.x >> 3) * 128 + w * 32;
    const float SCL = 0.125f * 1.4426950408889634f;
    v8s qf[2][2];
    #pragma unroll
    for (int u = 0; u < 2; ++u) {
        const float* qrow = Q + ((size_t)b * NS + q0 + 16 * u + lc) * ND + 8 * h;
        #pragma unroll
        for (int c = 0; c < 2; ++c) {
            v4f x0 = *(const v4f*)(qrow + 32 * c);
            v4f x1 = *(const v4f*)(qrow + 32 * c + 4);
            qf[u][c] = pk8(x0 * SCL, x1 * SCL);
        }
    }
    v4f o[2][4];
    #pragma unroll
    for (int u = 0; u < 2; ++u)
        #pragma unroll
        for (int g = 0; g < 4; ++g) o[u][g] = (v4f){0.f, 0.f, 0.f, 0.f};
    float m[2] = {-INFINITY, -INFINITY};
    float lsum[2] = {0.f, 0.f};
    for (int kt = 0; kt < NS / 64; ++kt) {
        const int k0 = kt * 64;
        __syncthreads();
        #pragma unroll
        for (int i = 0; i < 4; ++i) {
            int n = i * 256 + t;
            int row = n >> 4, c4 = (n & 15) * 4;
            v4f x = *(const v4f*)(K + ((size_t)b * NS + k0 + row) * ND + c4);
            *(v4s*)&Ksh[row][c4] = pk4(x[0], x[1], x[2], x[3]);
        }
        const int sr = t >> 4, sc4 = t & 15;
        float xv[4][4];
        #pragma unroll
        for (int i = 0; i < 4; ++i) {
            v4f x = *(const v4f*)(V + ((size_t)b * NS + k0 + sr * 4 + i) * ND + sc4 * 4);
            xv[i][0] = x[0]; xv[i][1] = x[1]; xv[i][2] = x[2]; xv[i][3] = x[3];
        }
        #pragma unroll
        for (int j = 0; j < 4; ++j)
            *(v4s*)&Vsh[sc4 * 4 + j][sr * 4] = pk4(xv[0][j], xv[1][j], xv[2][j], xv[3][j]);
        __syncthreads();
        float p[2][4][4];
        #pragma unroll
        for (int g = 0; g < 4; ++g) {
            v4f a0 = (v4f){0.f, 0.f, 0.f, 0.f};
            v4f a1 = (v4f){0.f, 0.f, 0.f, 0.f};
            #pragma unroll
            for (int c = 0; c < 2; ++c) {
                v8s ka = *(const v8s*)&Ksh[16 * g + lc][32 * c + 8 * h];
                a0 = __builtin_amdgcn_mfma_f32_16x16x32_bf16(ka, qf[0][c], a0, 0, 0, 0);
                a1 = __builtin_amdgcn_mfma_f32_16x16x32_bf16(ka, qf[1][c], a1, 0, 0, 0);
            }
            #pragma unroll
            for (int r = 0; r < 4; ++r) { p[0][g][r] = a0[r]; p[1][g][r] = a1[r]; }
        }
        #pragma unroll
        for (int u = 0; u < 2; ++u) {
            float pm = p[u][0][0];
            #pragma unroll
            for (int g = 0; g < 4; ++g)
                #pragma unroll
                for (int r = 0; r < 4; ++r) pm = fmaxf(pm, p[u][g][r]);
            pm = fmaxf(pm, __shfl_xor(pm, 16));
            pm = fmaxf(pm, __shfl_xor(pm, 32));
            if (__any(pm > m[u] + 8.0f)) {
                float mn = fmaxf(m[u], pm);
                float al = __builtin_amdgcn_exp2f(m[u] - mn);
                #pragma unroll
                for (int g = 0; g < 4; ++g) o[u][g] = o[u][g] * al;
                lsum[u] *= al;
                m[u] = mn;
            }
            float rs = 0.f;
            #pragma unroll
            for (int g = 0; g < 4; ++g)
                #pragma unroll
                for (int r = 0; r < 4; ++r) {
                    p[u][g][r] = __builtin_amdgcn_exp2f(p[u][g][r] - m[u]);
                    rs += p[u][g][r];
                }
            lsum[u] += rs;
        }
        #pragma unroll
        for (int c2 = 0; c2 < 2; ++c2) {
            union { v4s q[2]; v8s v; } pb0, pb1;
            pb0.q[0] = pk4(p[0][2*c2][0],   p[0][2*c2][1],   p[0][2*c2][2],   p[0][2*c2][3]);
            pb0.q[1] = pk4(p[0][2*c2+1][0], p[0][2*c2+1][1], p[0][2*c2+1][2], p[0][2*c2+1][3]);
            pb1.q[0] = pk4(p[1][2*c2][0],   p[1][2*c2][1],   p[1][2*c2][2],   p[1][2*c2][3]);
            pb1.q[1] = pk4(p[1][2*c2+1][0], p[1][2*c2+1][1], p[1][2*c2+1][2], p[1][2*c2+1][3]);
            #pragma unroll
            for (int g = 0; g < 4; ++g) {
                union { v4s q[2]; v8s v; } va;
                va.q[0] = *(const v4s*)&Vsh[16 * g + lc][32 * c2 + 4 * h];
                va.q[1] = *(const v4s*)&Vsh[16 * g + lc][32 * c2 + 16 + 4 * h];
                o[0][g] = __builtin_amdgcn_mfma_f32_16x16x32_bf16(va.v, pb0.v, o[0][g], 0, 0, 0);
                o[1][g] = __builtin_amdgcn_mfma_f32_16x16x32_bf16(va.v, pb1.v, o[1][g], 0, 0, 0);
            }
        }
    }
    #pragma unroll
    for (int u = 0; u < 2; ++u) {
        float ls = lsum[u];
        ls += __shfl_xor(ls, 16);
        ls += __shfl_xor(ls, 32);
        float inv = 1.0f / ls;
        float* orow = O + ((size_t)b * NS + q0 + 16 * u + lc) * ND;
        #pragma unroll
        for (int g = 0; g < 4; ++g) {
            v4f rr = o[u][g] * inv;
            *(v4f*)(orow + 16 * g + 4 * h) = rr;
        }
    }
}

extern "C" void kernel_launch(void* const* d_in, const int* in_sizes, int n_in,
                              void* d_out, int out_size, void* d_ws, size_t ws_size,
                              hipStream_t stream) {
    const float* q = (const float*)d_in[0];
    const float* k = (const float*)d_in[1];
    const float* v = (const float*)d_in[2];
    float* out = (float*)d_out;

    const size_t tot   = (size_t)NB * NS * ND;             // 2,097,152
    const size_t base  = 3 * tot * sizeof(short);          // 12 MB  (Qbf,Kbf,Vt)
    const size_t per_s = tot * sizeof(float) + (size_t)NROW * sizeof(float2);
    const size_t need4 = base + 4 * per_s;                 // ~45 MB
    const size_t need2 = base + 2 * per_s;                 // ~28.5 MB

    if (ws_size < base) {
        hipLaunchKernelGGL(fa_fallback, dim3(NB * (NS / 128)), dim3(256), 0, stream,
                           q, k, v, out);
        return;
    }

    short* qbf = (short*)d_ws;
    short* kbf = qbf + tot;
    short* vtb = kbf + tot;
    float* opart = (float*)(vtb + tot);

    hipLaunchKernelGGL(prep_q, dim3((unsigned)(tot / 2048)), dim3(256), 0, stream, q, qbf);
    hipLaunchKernelGGL(prep_k, dim3((unsigned)(tot / 2048)), dim3(256), 0, stream, k, kbf);
    hipLaunchKernelGGL(prep_v, dim3(NB * (NS / 64)), dim3(256), 0, stream, v, vtb);

    if (ws_size >= need4) {
        float2* stats = (float2*)(opart + 4 * tot);
        hipLaunchKernelGGL(fa_main<4>, dim3(NB * 32 * 4), dim3(256), 0, stream,
                           qbf, kbf, vtb, out, opart, stats);
        hipLaunchKernelGGL(fa_combine, dim3(NROW * 16 / 256), dim3(256), 0, stream,
                           opart, stats, out, 4);
    } else if (ws_size >= need2) {
        float2* stats = (float2*)(opart + 2 * tot);
        hipLaunchKernelGGL(fa_main<2>, dim3(NB * 32 * 2), dim3(256), 0, stream,
                           qbf, kbf, vtb, out, opart, stats);
        hipLaunchKernelGGL(fa_combine, dim3(NROW * 16 / 256), dim3(256), 0, stream,
                           opart, stats, out, 2);
    } else {
        hipLaunchKernelGGL(fa_main<1>, dim3(NB * 32), dim3(256), 0, stream,
                           qbf, kbf, vtb, out, (float*)nullptr, (float2*)nullptr);
    }
}